// Round 5
// baseline (312.318 us; speedup 1.0000x reference)
//
#include <hip/hip_runtime.h>
#include <hip/hip_bf16.h>

#define TOKENS 4096
#define OUTN   4096
#define INK    4096
#define RANK   16
// K padded: 4096 data + 16 lora + 48 zeros = 4160 (multiple of BK=64)
#define KP     4160
#define NT     (KP/64)   // 65 K-tiles

typedef __attribute__((ext_vector_type(8))) short short8;
typedef __attribute__((ext_vector_type(4))) float f32x4;

__device__ __constant__ float NF4_TAB[16] = {
  -1.0f, -0.6961928009986877f, -0.5250730514526367f, -0.39491748809814453f,
  -0.28444138169288635f, -0.18477343022823334f, -0.09105003625154495f, 0.0f,
  0.07958029955625534f, 0.16093020141124725f, 0.24611230194568634f, 0.33791524171829224f,
  0.44070982933044434f, 0.5626170039176941f, 0.7229568362236023f, 1.0f };

__device__ __forceinline__ unsigned short f2bf(float f) {
  unsigned int u = __float_as_uint(f);
  u += 0x7FFFu + ((u >> 16) & 1u);   // RNE; inputs are finite/normal
  return (unsigned short)(u >> 16);
}

// ---------------------------------------------------------------- fused: cast x->bf16 AND xa = x@A^T
__global__ __launch_bounds__(256) void prep_x_kernel(const float* __restrict__ x,
                                                     const float* __restrict__ loraA,
                                                     unsigned short* __restrict__ Xbf) {
  const int r0 = blockIdx.x * 4;
  const int t = threadIdx.x;
  const int lane = t & 63;
  const int wave = t >> 6;

  float xv[4][16];
  #pragma unroll
  for (int rv = 0; rv < 4; ++rv) {
    const float* xrow = x + (size_t)(r0 + rv) * INK;
    unsigned short* brow = Xbf + (size_t)(r0 + rv) * KP;
    #pragma unroll
    for (int q = 0; q < 4; ++q) {
      const int e0 = q * 1024 + t * 4;
      float4 v = *(const float4*)(xrow + e0);
      xv[rv][q * 4 + 0] = v.x; xv[rv][q * 4 + 1] = v.y;
      xv[rv][q * 4 + 2] = v.z; xv[rv][q * 4 + 3] = v.w;
      ushort4 o; o.x = f2bf(v.x); o.y = f2bf(v.y); o.z = f2bf(v.z); o.w = f2bf(v.w);
      *(ushort4*)(brow + e0) = o;
    }
  }

  float p[4][16];
  #pragma unroll
  for (int a = 0; a < 4; ++a)
    #pragma unroll
    for (int b = 0; b < 16; ++b) p[a][b] = 0.f;

  #pragma unroll
  for (int rr = 0; rr < 16; ++rr) {
    const float* arow = loraA + (size_t)rr * INK;
    float av[16];
    #pragma unroll
    for (int q = 0; q < 4; ++q) {
      float4 v = *(const float4*)(arow + q * 1024 + t * 4);
      av[q * 4 + 0] = v.x; av[q * 4 + 1] = v.y;
      av[q * 4 + 2] = v.z; av[q * 4 + 3] = v.w;
    }
    #pragma unroll
    for (int rv = 0; rv < 4; ++rv) {
      float s = 0.f;
      #pragma unroll
      for (int j = 0; j < 16; ++j) s += xv[rv][j] * av[j];
      p[rv][rr] += s;
    }
  }

  #pragma unroll
  for (int rv = 0; rv < 4; ++rv)
    #pragma unroll
    for (int rr = 0; rr < 16; ++rr) {
      float v = p[rv][rr];
      v += __shfl_xor(v, 32); v += __shfl_xor(v, 16); v += __shfl_xor(v, 8);
      v += __shfl_xor(v, 4);  v += __shfl_xor(v, 2);  v += __shfl_xor(v, 1);
      p[rv][rr] = v;
    }
  __shared__ float red[4][64];
  if (lane == 0) {
    #pragma unroll
    for (int rv = 0; rv < 4; ++rv)
      #pragma unroll
      for (int rr = 0; rr < 16; ++rr) red[wave][rv * 16 + rr] = p[rv][rr];
  }
  __syncthreads();
  if (t < 64) {
    float s = red[0][t] + red[1][t] + red[2][t] + red[3][t];
    int rv = t >> 4, rr = t & 15;
    Xbf[(size_t)(r0 + rv) * KP + INK + rr] = f2bf(s);
  }
}

// ---------------------------------------------------------------- W dequant -> bf16 (+2*B append)
__global__ __launch_bounds__(256) void prep_w_kernel(const int* __restrict__ codes,
                                                     const float* __restrict__ scales,
                                                     const float* __restrict__ loraB,
                                                     unsigned short* __restrict__ Wbf) {
  __shared__ float tab[16];
  int t = threadIdx.x;
  if (t < 16) tab[t] = NF4_TAB[t];
  __syncthreads();
  const int row = blockIdx.x;
  const int* crow = codes + (size_t)row * INK;
  const float* srow = scales + (row << 6);
  unsigned short* wrow = Wbf + (size_t)row * KP;
  #pragma unroll
  for (int q = 0; q < 4; ++q) {
    const int e0 = q * 1024 + t * 4;
    int4 c = *(const int4*)(crow + e0);
    float sc = srow[e0 >> 6];
    ushort4 o;
    o.x = f2bf(tab[c.x] * sc);
    o.y = f2bf(tab[c.y] * sc);
    o.z = f2bf(tab[c.z] * sc);
    o.w = f2bf(tab[c.w] * sc);
    *(ushort4*)(wrow + e0) = o;
  }
  if (t < RANK) {                                 // SCALING = 2.0 folded here
    wrow[INK + t] = f2bf(2.0f * loraB[row * RANK + t]);
  } else if (t < 64) {
    wrow[4112 + (t - 16)] = 0;                    // zero pad cols [4112,4160)
  }
}

// ---------------------------------------------------------------- 256x256 8-phase bf16 MFMA GEMM
// Same schedule as R4, but fragment loads are inline-asm ds_read_b128 — opaque
// to the compiler's LDS alias analysis, so it cannot insert conservative
// s_waitcnt vmcnt(0) drains between global_load_lds prefetch and the reads.
// Discipline is fully manual: asm vmcnt(6)/vmcnt(0) per tile, asm lgkmcnt(0)
// after the pre-MFMA barrier, sched_barrier(0) right after (rule #18: prevents
// hipcc hoisting register-only MFMA past the inline-asm wait).
#define STAGE2(BASE, OFFS, LDSB, BUF, H, KT)                                               \
  do {                                                                                     \
    __builtin_amdgcn_global_load_lds(                                                      \
        (const __attribute__((address_space(1))) void*)((BASE) + (OFFS)[H][0] + (KT)*128), \
        (__attribute__((address_space(3))) void*)((LDSB) + (BUF)*32768 + (H)*16384 + tid*16), 16, 0, 0); \
    __builtin_amdgcn_global_load_lds(                                                      \
        (const __attribute__((address_space(1))) void*)((BASE) + (OFFS)[H][1] + (KT)*128), \
        (__attribute__((address_space(3))) void*)((LDSB) + (BUF)*32768 + (H)*16384 + 8192 + tid*16), 16, 0, 0); \
  } while (0)

#define DSREAD(D, PTR)                                                                     \
  asm volatile("ds_read_b128 %0, %1"                                                      \
               : "=&v"(D)                                                                  \
               : "v"((const __attribute__((address_space(3))) char*)(PTR)))

__global__ __launch_bounds__(512, 2) void gemm_kernel(const unsigned short* __restrict__ Xbf,
                                                      const unsigned short* __restrict__ Wbf,
                                                      float* __restrict__ out) {
  extern __shared__ char lds[];
  char* ldsA = lds;            // 65536 B
  char* ldsB = lds + 65536;    // 65536 B
  const int tid  = threadIdx.x;
  const int lane = tid & 63;
  const int wave = tid >> 6;
  const int wr = wave >> 2;    // 0..1
  const int wc = wave & 3;     // 0..3
  const int brow = blockIdx.y * 256;
  const int bcol = blockIdx.x * 256;

  // ---- staging global voffsets (bytes), per [half][j]
  unsigned int aoffg[2][2], boffg[2][2];
  #pragma unroll
  for (int h = 0; h < 2; ++h)
    #pragma unroll
    for (int j = 0; j < 2; ++j) {
      int ci  = j * 512 + tid;            // 16B-chunk index 0..1023
      int lr  = ci >> 3;                  // local row 0..127
      int gkc = (ci & 7) ^ (lr & 7);      // pre-swizzled source chunk
      int growA = (lr & 63) | (h << 6) | ((lr >> 6) << 7);
      int growB = (lr & 31) | (h << 5) | ((lr >> 5) << 6);
      aoffg[h][j] = (unsigned)growA * (KP * 2) + gkc * 16;
      boffg[h][j] = (unsigned)growB * (KP * 2) + gkc * 16;
    }
  const char* baseA = (const char*)Xbf + (size_t)brow * (KP * 2);
  const char* baseB = (const char*)Wbf + (size_t)bcol * (KP * 2);

  // ---- fragment ds_read offsets (within one operand buffer)
  unsigned int aoff[8][2], boff[4][2];
  #pragma unroll
  for (int m = 0; m < 8; ++m) {
    int R = wr * 128 + m * 16 + (lane & 15);
    int h = (R >> 6) & 1;
    int lr = (R & 63) | ((R >> 7) << 6);
    #pragma unroll
    for (int s = 0; s < 2; ++s) {
      int c = s * 4 + (lane >> 4);
      aoff[m][s] = h * 16384 + lr * 128 + ((c ^ (lr & 7)) * 16);
    }
  }
  #pragma unroll
  for (int n = 0; n < 4; ++n) {
    int C = wc * 64 + n * 16 + (lane & 15);
    int h = (C >> 5) & 1;
    int lc = (C & 31) | ((C >> 6) << 5);
    #pragma unroll
    for (int s = 0; s < 2; ++s) {
      int c = s * 4 + (lane >> 4);
      boff[n][s] = h * 16384 + lc * 128 + ((c ^ (lc & 7)) * 16);
    }
  }

  f32x4 acc[8][4];
  #pragma unroll
  for (int m = 0; m < 8; ++m)
    #pragma unroll
    for (int n = 0; n < 4; ++n) acc[m][n] = (f32x4){0.f, 0.f, 0.f, 0.f};

  // ---- prologue: tile0 (A0,B0,A1,B1) + tile1 (A0,B0,A1)  -> 14 loads
  STAGE2(baseA, aoffg, ldsA, 0, 0, 0);
  STAGE2(baseB, boffg, ldsB, 0, 0, 0);
  STAGE2(baseA, aoffg, ldsA, 0, 1, 0);
  STAGE2(baseB, boffg, ldsB, 0, 1, 0);
  STAGE2(baseA, aoffg, ldsA, 1, 0, 1);
  STAGE2(baseB, boffg, ldsB, 1, 0, 1);
  STAGE2(baseA, aoffg, ldsA, 1, 1, 1);
  asm volatile("s_waitcnt vmcnt(6)" ::: "memory");   // retire tile0's 8 loads
  __builtin_amdgcn_s_barrier();

  short8 a_set[4][2], b0s[2][2], b1s[2][2];

  for (int t = 0; t < NT; ++t) {
    const int buf = t & 1;
    const char* A  = ldsA + buf * 32768;
    const char* Bb = ldsB + buf * 32768;

    // ---------- phase 0: read A-h0 (m0-3) + B-h0 (n0-1); stage B1(t+1)
    #pragma unroll
    for (int m = 0; m < 4; ++m) {
      DSREAD(a_set[m][0], A + aoff[m][0]);
      DSREAD(a_set[m][1], A + aoff[m][1]);
    }
    #pragma unroll
    for (int n = 0; n < 2; ++n) {
      DSREAD(b0s[n][0], Bb + boff[n][0]);
      DSREAD(b0s[n][1], Bb + boff[n][1]);
    }
    if (t + 1 < NT) STAGE2(baseB, boffg, ldsB, (buf ^ 1), 1, t + 1);
    __builtin_amdgcn_s_barrier();
    asm volatile("s_waitcnt lgkmcnt(0)" ::: "memory");
    __builtin_amdgcn_sched_barrier(0);
    __builtin_amdgcn_s_setprio(1);
    #pragma unroll
    for (int s = 0; s < 2; ++s)
      #pragma unroll
      for (int m = 0; m < 4; ++m)
        #pragma unroll
        for (int n = 0; n < 2; ++n)
          acc[m][n] = __builtin_amdgcn_mfma_f32_16x16x32_bf16(a_set[m][s], b0s[n][s], acc[m][n], 0, 0, 0);
    __builtin_amdgcn_s_setprio(0);
    __builtin_amdgcn_s_barrier();

    // ---------- phase 1: read B-h1 (n2-3); stage A0(t+2)
    #pragma unroll
    for (int n = 0; n < 2; ++n) {
      DSREAD(b1s[n][0], Bb + boff[2 + n][0]);
      DSREAD(b1s[n][1], Bb + boff[2 + n][1]);
    }
    if (t + 2 < NT) STAGE2(baseA, aoffg, ldsA, buf, 0, t + 2);
    __builtin_amdgcn_s_barrier();
    asm volatile("s_waitcnt lgkmcnt(0)" ::: "memory");
    __builtin_amdgcn_sched_barrier(0);
    __builtin_amdgcn_s_setprio(1);
    #pragma unroll
    for (int s = 0; s < 2; ++s)
      #pragma unroll
      for (int m = 0; m < 4; ++m)
        #pragma unroll
        for (int n = 0; n < 2; ++n)
          acc[m][2 + n] = __builtin_amdgcn_mfma_f32_16x16x32_bf16(a_set[m][s], b1s[n][s], acc[m][2 + n], 0, 0, 0);
    __builtin_amdgcn_s_setprio(0);
    __builtin_amdgcn_s_barrier();

    // ---------- phase 2: read A-h1 (m4-7); stage B0(t+2)
    #pragma unroll
    for (int m = 0; m < 4; ++m) {
      DSREAD(a_set[m][0], A + aoff[4 + m][0]);
      DSREAD(a_set[m][1], A + aoff[4 + m][1]);
    }
    if (t + 2 < NT) STAGE2(baseB, boffg, ldsB, buf, 0, t + 2);
    __builtin_amdgcn_s_barrier();
    asm volatile("s_waitcnt lgkmcnt(0)" ::: "memory");
    __builtin_amdgcn_sched_barrier(0);
    __builtin_amdgcn_s_setprio(1);
    #pragma unroll
    for (int s = 0; s < 2; ++s)
      #pragma unroll
      for (int m = 0; m < 4; ++m)
        #pragma unroll
        for (int n = 0; n < 2; ++n)
          acc[4 + m][n] = __builtin_amdgcn_mfma_f32_16x16x32_bf16(a_set[m][s], b0s[n][s], acc[4 + m][n], 0, 0, 0);
    __builtin_amdgcn_s_setprio(0);
    __builtin_amdgcn_s_barrier();

    // ---------- phase 3: stage A1(t+2); counted vmcnt; MFMA (m4-7, n2-3)
    if (t + 2 < NT) STAGE2(baseA, aoffg, ldsA, buf, 1, t + 2);
    if (t >= NT - 2) asm volatile("s_waitcnt vmcnt(0)" ::: "memory");
    else             asm volatile("s_waitcnt vmcnt(6)" ::: "memory");
    __builtin_amdgcn_s_barrier();
    __builtin_amdgcn_s_setprio(1);
    #pragma unroll
    for (int s = 0; s < 2; ++s)
      #pragma unroll
      for (int m = 0; m < 4; ++m)
        #pragma unroll
        for (int n = 0; n < 2; ++n)
          acc[4 + m][2 + n] = __builtin_amdgcn_mfma_f32_16x16x32_bf16(a_set[m][s], b1s[n][s], acc[4 + m][2 + n], 0, 0, 0);
    __builtin_amdgcn_s_setprio(0);
    __builtin_amdgcn_s_barrier();
  }

  // ---- epilogue: C/D layout col=lane&15, row=(lane>>4)*4+j
  #pragma unroll
  for (int m = 0; m < 8; ++m) {
    int row = brow + wr * 128 + m * 16 + ((lane >> 4) << 2);
    #pragma unroll
    for (int n = 0; n < 4; ++n) {
      int col = bcol + wc * 64 + n * 16 + (lane & 15);
      #pragma unroll
      for (int j = 0; j < 4; ++j)
        out[(size_t)(row + j) * OUTN + col] = acc[m][n][j];
    }
  }
}

extern "C" void kernel_launch(void* const* d_in, const int* in_sizes, int n_in,
                              void* d_out, int out_size, void* d_ws, size_t ws_size,
                              hipStream_t stream) {
  const float* x      = (const float*)d_in[0];
  const int*   codes  = (const int*)d_in[1];
  const float* scales = (const float*)d_in[2];
  const float* loraA  = (const float*)d_in[3];
  const float* loraB  = (const float*)d_in[4];
  float* out = (float*)d_out;

  unsigned short* Xbf = (unsigned short*)d_ws;                 // 4096*4160*2 B
  unsigned short* Wbf = Xbf + (size_t)TOKENS * KP;             // 4096*4160*2 B  (total ~65 MB)

  prep_x_kernel<<<TOKENS / 4, 256, 0, stream>>>(x, loraA, Xbf);
  prep_w_kernel<<<OUTN, 256, 0, stream>>>(codes, scales, loraB, Wbf);

  static_cast<void>(hipFuncSetAttribute((const void*)gemm_kernel,
                    hipFuncAttributeMaxDynamicSharedMemorySize, 131072));
  dim3 grid(OUTN / 256, TOKENS / 256);
  gemm_kernel<<<grid, 512, 131072, stream>>>(Xbf, Wbf, out);
}